// Round 11
// baseline (122.054 us; speedup 1.0000x reference)
//
#include <hip/hip_runtime.h>
#include <math.h>

// ConvCaps EM routing, fp32 I/O. n=392 positions, one 512-thread block each.
// R31 = R30 resubmit (R30 bench was an infra failure — container died twice,
// kernel never measured; no toolchain risk in this source: all intrinsics
// compiled+passed in R26/R28).
// R30: R26 (best measured 73.5us) + the two VERIFIED-SAFE diet items from R29,
// with __shfl_xor(,16) tails restored everywhere.
//  (1) Loop-invariant addressing hoist in sweeps 1,2: sw = ((kt*16+ks)>>1)&3
//      == (ks>>1)&3 (8*kt = 0 mod 4) -> Pi: 4 walking pointers += 256 floats/
//      body; W: wp += 2048 float4s/body; fA: walking LDS ptr. ~8-10 VALU/body.
//  (2) quad split into 2 parallel FMA chains (halves serial depth; this
//      reassociation already passed in R28, absmax 0.00195).
// PERMANENT BAN: v_permlane16_swap xor16 — R25 and R29 (distinct-SSA operands)
// produced the IDENTICAL wrong output (absmax 468/2.2988): the instruction
// does not implement the modeled xor16 exchange; both halves come back as the
// same row-swapped vector (sum = 2*x[i^16]). Measurement beats the ISA doc.
// HARD CONSTRAINT: VGPR <= 128 (2 blocks/CU). No launch_bounds min-waves
// (R21: 40-VGPR clamp + 1GB spills).
// Dead ends (measured): 768-thread (R21-23); min-waves (R3/R8/R21); ping-pong
// w/ B2-in-LDS + volatile asm fences (R27: 77us); deferred-moments (R28:
// neutral); permlane16_swap (R25/R29); LDS prefetch w/o consumer move (R12);
// 2 pos/block (R7); k-interleave (R16/R19); A/B-in-LDS @768th (R22/R23).
// Plateau note: 3 ILP restructures (R26/27/28) all left VALUBusy 39-43% —
// if this diet round also lands >=73us the structure is at its practical
// latency plateau.

#define NTH 512
#define KK 288
#define KSG 16       // k-groups (512/32)
#define KT 18        // 288 / 16
#define CC 32
#define PS 16
#define EPSF 1e-8f
#define LAMF 1e-3f
#define HL2PI 0.91893853320467274178f   // 0.5*ln(2*pi)
#define LOG2E 1.4426950408889634f

typedef float v2f __attribute__((ext_vector_type(2)));

__device__ __forceinline__ float4 ld4(const float* p){ return *(const float4*)p; }
__device__ __forceinline__ float rcpf(float x){ return __builtin_amdgcn_rcpf(x); }
__device__ __forceinline__ v2f bc2(float s){ return (v2f){s, s}; }
__device__ __forceinline__ v2f fma2(v2f a, v2f b, v2f c){ return __builtin_elementwise_fma(a, b, c); }

// DPP cross-lane reduce steps (VALU pipe ~2-4cyc vs ds_swizzle ~30cyc).
template<int CTRL>
__device__ __forceinline__ float dpp_add(float x){
  const int p = __builtin_amdgcn_update_dpp(0, __builtin_bit_cast(int, x),
                                            CTRL, 0xF, 0xF, true);
  return x + __builtin_bit_cast(float, p);
}
template<int CTRL>
__device__ __forceinline__ float dpp_max(float x){
  const int p = __builtin_amdgcn_update_dpp(0, __builtin_bit_cast(int, x),
                                            CTRL, 0xF, 0xF, true);
  return fmaxf(x, __builtin_bit_cast(float, p));
}
__device__ __forceinline__ float sum32(float s){
  s = dpp_add<0xB1>(s); s = dpp_add<0x4E>(s);
  s = dpp_add<0x141>(s); s = dpp_add<0x140>(s);
  s += __shfl_xor(s, 16);
  return s;
}

extern "C" __global__ void __launch_bounds__(NTH)
convcaps_em_kernel(const float* __restrict__ x, const float* __restrict__ wgt,
                   const float* __restrict__ beta_a, const float* __restrict__ beta_u,
                   float* __restrict__ out)
{
  __shared__ float sP[KK*PS];        // poses, xor-swizzled groups (18432 B)
  __shared__ float sA[KK];           // f = a/(a+eps) (1152 B)
  __shared__ float sPart[8*CC*33];   // wave partials t0|t1[16]|t2[16] (33792 B)
  __shared__ float sMu[CC*17];       // (2176 B)
  __shared__ float sNI2[CC*17];      // -0.5/sigma^2 (2176 B)
  __shared__ float sLs[CC], sLnA[CC], sAo[CC];   // 384 B
  // total ~58.1 KB -> 2 blocks/CU

  const int tid = threadIdx.x;
  const int n   = blockIdx.x;
  const int b   = n / 49;
  const int r49 = n - b*49;
  const int ohi = r49 / 7;
  const int owi = r49 - ohi*7;

  const float* xw = x + ((size_t)b*16 + (size_t)(ohi*2))*16*544 + (size_t)(owi*2)*544;

  const int c  = tid & 31;    // sweep layout: c in-wave (softmax over c)
  const int ks = tid >> 5;    // k-group 0..15
  const int w  = tid >> 6;    // wave 0..7
  const int cc = tid >> 4;    // stats layout: one thread per (cc, pp)
  const int pp = tid & 15;

  // ---- stage poses (xor-swizzled groups) ----
  for (int idx = tid; idx < KK*PS/4; idx += NTH) {   // 1152 float4s
    const int sp  = idx >> 7;
    const int ch4 = idx & 127;
    const int kh = sp/3, kw = sp - kh*3;
    const float4 v = ld4(&xw[kh*(16*544) + kw*544 + ch4*4]);
    const int k = sp*32 + (ch4 >> 2);
    const int g = ch4 & 3;
    *(float4*)&sP[(k<<4) + ((g ^ ((k>>1)&3))<<2)] = v;
  }
  // ---- stage activations ----
  if (tid < KK/4) {
    const int sp  = tid >> 3;
    const int bc4 = tid & 7;
    const int kh = sp/3, kw = sp - kh*3;
    const float4 v = ld4(&xw[kh*(16*544) + kw*544 + 512 + bc4*4]);
    *(float4*)&sA[sp*32 + bc4*4] = v;
  }
  __syncthreads();
  if (tid < KK) { const float a = sA[tid]; sA[tid] = a * rcpf(a + EPSF); }
  __syncthreads();

  float t0;
  v2f t1[8], t2[8];    // packed moment accumulators

  // ---- stats phase (R6-proven layout; unpack pairs at store) ----
  auto stats = [&](){
    t0 += __shfl_xor(t0, 32);
#pragma unroll
    for (int q = 0; q < 8; ++q) {
      t1[q].x += __shfl_xor(t1[q].x, 32);
      t1[q].y += __shfl_xor(t1[q].y, 32);
      t2[q].x += __shfl_xor(t2[q].x, 32);
      t2[q].y += __shfl_xor(t2[q].y, 32);
    }
    if ((tid & 32) == 0) {
      float* pr = &sPart[(w*CC + c)*33];
      pr[0] = t0;
#pragma unroll
      for (int q = 0; q < 8; ++q) {
        pr[1 + 2*q]     = t1[q].x;  pr[1 + 2*q + 1]  = t1[q].y;
        pr[17 + 2*q]    = t2[q].x;  pr[17 + 2*q + 1] = t2[q].y;
      }
    }
    __syncthreads();
    {
      float T0 = 0.f, T1 = 0.f, T2 = 0.f;
#pragma unroll
      for (int j = 0; j < 8; ++j) {
        const float* pr = &sPart[(j*CC + cc)*33];
        T0 += pr[0]; T1 += pr[1+pp]; T2 += pr[17+pp];
      }
      const float z   = rcpf(T0 + EPSF);
      const float mu  = T1 * z;
      const float s0  = T0 * z;
      const float var = fmaxf(T2*z - mu*mu*(2.f - s0), 0.f) + EPSF;
      sMu[cc*17 + pp]  = mu;
      sNI2[cc*17 + pp] = -0.5f * rcpf(var);
      float lsum = 0.5f * __logf(var);
      lsum = dpp_add<0xB1>(lsum); lsum = dpp_add<0x4E>(lsum);
      lsum = dpp_add<0x141>(lsum); lsum = dpp_add<0x140>(lsum);
      if (pp == 0) {
        const float cost = (16.f*beta_u[cc] + lsum) * T0;   // r_sum = T0
        const float ao = rcpf(1.f + __expf(-(LAMF*(beta_a[cc] - cost))));
        sAo[cc] = ao; sLnA[cc] = __logf(ao); sLs[cc] = lsum;
      }
    }
    __syncthreads();
  };

  const float4* wg4 = (const float4*)wgt;

  // v = P@W for one k into 8 packed v2f (16 fp32)
  auto compute_v = [&](v2f (&v)[8], const float4 (&P)[4],
                       const float4& W0, const float4& W1,
                       const float4& W2, const float4& W3){
    const v2f w0lo = {W0.x,W0.y}, w0hi = {W0.z,W0.w};
    const v2f w1lo = {W1.x,W1.y}, w1hi = {W1.z,W1.w};
    const v2f w2lo = {W2.x,W2.y}, w2hi = {W2.z,W2.w};
    const v2f w3lo = {W3.x,W3.y}, w3hi = {W3.z,W3.w};
#pragma unroll
    for (int i = 0; i < 4; ++i) {
      v2f lo = bc2(P[i].x) * w0lo;
      lo = fma2(bc2(P[i].y), w1lo, lo);
      lo = fma2(bc2(P[i].z), w2lo, lo);
      lo = fma2(bc2(P[i].w), w3lo, lo);
      v2f hi = bc2(P[i].x) * w0hi;
      hi = fma2(bc2(P[i].y), w1hi, hi);
      hi = fma2(bc2(P[i].z), w2hi, hi);
      hi = fma2(bc2(P[i].w), w3hi, hi);
      v[i*2] = lo; v[i*2+1] = hi;
    }
  };

  // ---- sweep 0 (it=0): r uniform -> rr = f/32, W software-pipelined ----
  // (kept exactly as R26 — proven; diet applied only to sweeps 1,2)
  t0 = 0.f;
#pragma unroll
  for (int q = 0; q < 8; ++q) { t1[q] = bc2(0.f); t2[q] = bc2(0.f); }
  {
    float4 cw0, cw1, cw2, cw3;
    {
      const size_t base = ((size_t)(ks*32 + c))*4;   // kt=0 -> k=ks
      cw0 = wg4[base]; cw1 = wg4[base+1]; cw2 = wg4[base+2]; cw3 = wg4[base+3];
    }
#pragma unroll 1
    for (int kt = 0; kt < KT; ++kt) {
      const int k = kt*KSG + ks;
      const int kn = ((kt+1 < KT) ? kt+1 : kt)*KSG + ks;
      float4 nw0, nw1, nw2, nw3;
      {
        const size_t base = ((size_t)(kn*32 + c))*4;
        nw0 = wg4[base]; nw1 = wg4[base+1]; nw2 = wg4[base+2]; nw3 = wg4[base+3];
      }
      const v2f w0lo = {cw0.x,cw0.y}, w0hi = {cw0.z,cw0.w};
      const v2f w1lo = {cw1.x,cw1.y}, w1hi = {cw1.z,cw1.w};
      const v2f w2lo = {cw2.x,cw2.y}, w2hi = {cw2.z,cw2.w};
      const v2f w3lo = {cw3.x,cw3.y}, w3hi = {cw3.z,cw3.w};
      const int sw = (k>>1)&3;
      const float* pb = &sP[k<<4];
      const float4 Pi[4] = { ld4(pb + ((0^sw)<<2)), ld4(pb + ((1^sw)<<2)),
                             ld4(pb + ((2^sw)<<2)), ld4(pb + ((3^sw)<<2)) };
      const float rr = sA[k] * (1.0f/32.0f);
      t0 += rr;
      const v2f rr2 = bc2(rr);
#pragma unroll
      for (int i = 0; i < 4; ++i) {
        v2f lo = bc2(Pi[i].x) * w0lo;
        lo = fma2(bc2(Pi[i].y), w1lo, lo);
        lo = fma2(bc2(Pi[i].z), w2lo, lo);
        lo = fma2(bc2(Pi[i].w), w3lo, lo);
        v2f hi = bc2(Pi[i].x) * w0hi;
        hi = fma2(bc2(Pi[i].y), w1hi, hi);
        hi = fma2(bc2(Pi[i].z), w2hi, hi);
        hi = fma2(bc2(Pi[i].w), w3hi, hi);
        const v2f mlo = rr2 * lo, mhi = rr2 * hi;
        t1[i*2]   += mlo;  t2[i*2]   = fma2(mlo, lo, t2[i*2]);
        t1[i*2+1] += mhi;  t2[i*2+1] = fma2(mhi, hi, t2[i*2+1]);
      }
      cw0 = nw0; cw1 = nw1; cw2 = nw2; cw3 = nw3;
    }
  }
  stats();

  // ---- sweeps 1,2: R26 rotation + hoisted invariant addressing. ----
  const int swv = (ks>>1)&3;   // ((kt*16+ks)>>1)&3 == (ks>>1)&3: 8*kt = 0 mod 4
  for (int it = 1; it < 3; ++it) {
    // loop-invariant per (sweep, c): A = log2e*ni2, B = -2*log2e*ni2*mu,
    // G = log2e*(Sum ni2*mu^2 + lcv - M)
    v2f A2[8], B2[8];
    float gsum = 0.f;
#pragma unroll
    for (int q = 0; q < 8; ++q) {
      const v2f m2 = (v2f){ sMu[c*17 + 2*q],  sMu[c*17 + 2*q + 1] };
      const v2f n2 = (v2f){ sNI2[c*17 + 2*q], sNI2[c*17 + 2*q + 1] };
      const v2f nm = n2 * m2;
      A2[q] = bc2(LOG2E) * n2;
      B2[q] = bc2(-2.f*LOG2E) * nm;
      const v2f g2 = nm * m2;
      gsum += g2.x + g2.y;
    }
    float lcv = sLnA[c] - sLs[c] - 16.f*HL2PI;
    float M = lcv;
    M = dpp_max<0xB1>(M);  M = dpp_max<0x4E>(M);
    M = dpp_max<0x141>(M); M = dpp_max<0x140>(M);
    M = fmaxf(M, __shfl_xor(M, 16));
    const float G = LOG2E*(gsum + lcv - M);

    auto softmax_moments = [&](const v2f (&v)[8], float fA){
      v2f accA = bc2(0.f), accB = bc2(0.f);
#pragma unroll
      for (int q = 0; q < 8; q += 2) {      // 2 chains: halve serial depth
        accA = fma2(fma2(A2[q],   v[q],   B2[q]),   v[q],   accA);
        accB = fma2(fma2(A2[q+1], v[q+1], B2[q+1]), v[q+1], accB);
      }
      const float ex = (accA.x + accA.y) + (accB.x + accB.y) + G;
      const float e = exp2f(ex);            // log2-domain exponent <= ~0
      const float s = sum32(e);
      const float rr = e * rcpf(s + 1e-37f) * fA;   // r * a/(a+eps)
      t0 += rr;
      const v2f rr2 = bc2(rr);
#pragma unroll
      for (int q = 0; q < 8; ++q) {
        const v2f tmp = rr2 * v[q];
        t1[q] += tmp;
        t2[q] = fma2(tmp, v[q], t2[q]);
      }
    };

    t0 = 0.f;
#pragma unroll
    for (int q = 0; q < 8; ++q) { t1[q] = bc2(0.f); t2[q] = bc2(0.f); }

    // walking pointers (all advance by a compile-time constant per body)
    const float4* wp = wg4 + ((size_t)(ks*32 + c))*4;   // W(k), += 2048/body
    const float*  apf = &sA[ks];                        // fA(k-KSG), += 16/body
    const float*  p0 = &sP[(ks<<4) + ((0^swv)<<2)];     // Pi, += 256/body
    const float*  p1 = &sP[(ks<<4) + ((1^swv)<<2)];
    const float*  p2 = &sP[(ks<<4) + ((2^swv)<<2)];
    const float*  p3 = &sP[(ks<<4) + ((3^swv)<<2)];

    v2f vA[8];
    // prologue (kt=0): load W(k0)+Pi(k0), compute vA. Latency exposed once.
    {
      const float4 w0 = wp[0], w1 = wp[1], w2 = wp[2], w3 = wp[3];
      const float4 Pi[4] = { ld4(p0), ld4(p1), ld4(p2), ld4(p3) };
      compute_v(vA, Pi, w0, w1, w2, w3);
    }
#pragma unroll 1
    for (int kt = 1; kt < KT; ++kt) {
      // advance walking pointers (constant adds, independent)
      wp += (size_t)KSG*32*4;               // 2048 float4s
      p0 += KSG*PS; p1 += KSG*PS; p2 += KSG*PS; p3 += KSG*PS;
      // (1) issue W(k) from L2 — consumed after softmax
      const float4 w0 = wp[0], w1 = wp[1], w2 = wp[2], w3 = wp[3];
      // (2) issue sA(k-KSG) BEFORE Pi so its wait is lgkmcnt(4), not a drain
      const float fA = *apf;
      // (3) issue Pi(k) ds_reads — consumed after softmax
      const float4 Pi[4] = { ld4(p0), ld4(p1), ld4(p2), ld4(p3) };
      // (4) softmax + moments on previous k's v — pure VALU, hides (1)+(3)
      softmax_moments(vA, fA);
      apf += KSG;
      // (5) compute v(k) — waits land here
      compute_v(vA, Pi, w0, w1, w2, w3);
    }
    // epilogue: softmax+moments for the last k (apf now at (KT-1)*KSG+ks)
    softmax_moments(vA, *apf);
    stats();
  }

  // ---- epilogue ----
  out[(size_t)n*544 + tid] = sMu[(tid>>4)*17 + (tid&15)];
  if (tid < CC) out[(size_t)n*544 + 512 + tid] = sAo[tid];
}

extern "C" void kernel_launch(void* const* d_in, const int* in_sizes, int n_in,
                              void* d_out, int out_size, void* d_ws, size_t ws_size,
                              hipStream_t stream) {
  (void)in_sizes; (void)n_in; (void)d_ws; (void)ws_size; (void)out_size;
  const float* x  = (const float*)d_in[0];
  const float* w  = (const float*)d_in[1];
  const float* ba = (const float*)d_in[2];
  const float* bu = (const float*)d_in[3];
  float* out = (float*)d_out;
  convcaps_em_kernel<<<dim3(392), dim3(NTH), 0, stream>>>(x, w, ba, bu, out);
}

// Round 12
// 120.792 us; speedup vs baseline: 1.0104x; 1.0104x over previous
//
#include <hip/hip_runtime.h>
#include <math.h>

// ConvCaps EM routing, fp32 I/O. n=392 positions, one 512-thread block each.
// R32 = FINAL: exact revert to R26 (session-best, measured 73.5us dispatch /
// 119.8us bench; R0 baseline was 76.2/122.8).
// Structure: single fused kernel; sweep 0 with W software-pipeline; sweeps 1,2
// with 2-stage rotation (issue W(k)+sA(kp)+Pi(k) loads, run softmax+moments on
// PREVIOUS v — ~400cy pure-VALU chain hides L2 W latency + LDS Pi latency —
// then compute v(k)); packed fp32 (v_pk_fma); DPP butterflies + shfl_xor
// tails; shifted exp2 softmax with loop-invariant A/B/G quadratic form;
// xor-swizzled pose tiles; 8-wave partial merge in stats.
// Post-R26 scorecard (all measured, all reverted):
//   R27 ping-pong + B2-in-LDS + volatile-asm fences: 77.3us (fences block
//     interleave; LDS reads lengthen chain head).
//   R28 deferred-moments pipeline: 74.5us (neutral).
//   R31 walking-pointer hoist + 2-chain quad: 81.5us (fewer instructions,
//     MORE stall — R26's immediate-offset ds_reads + compiler LICM already
//     optimal; live pointer regs serialized on the critical path).
//   R21-23 768-thread: 85-594us. R25/R29 permlane16_swap xor16: WRONG OUTPUT
//     twice (identical absmax 2.2988 with independent operand strategies —
//     instruction does not implement the modeled exchange; PERMANENT BAN).
// Plateau: VALUBusy pinned 36-43% across ALL passing variants (TLP, 3 ILP
// reorders, diet). Residual = in-order serial EM chain (quad->exp2->5-hop
// reduce->rcp->rr gating moments) x 392-on-256 dispatch imbalance (crit-CU
// floor = 2 positions' chain work). Remaining outs judged not worth risk:
// bf16-MFMA compute_v (precision margin 0.00098 -> ~1e-2 vs 1.7e-2 threshold)
// and position-split blocks (blocked by EM's global per-position reduction).
// HARD RULES for future sessions: VGPR <= 128 (2 blocks/CU); NEVER use
// __launch_bounds__ min-waves arg (R21: 40-VGPR clamp + 1GB scratch spills).

#define NTH 512
#define KK 288
#define KSG 16       // k-groups (512/32)
#define KT 18        // 288 / 16
#define CC 32
#define PS 16
#define EPSF 1e-8f
#define LAMF 1e-3f
#define HL2PI 0.91893853320467274178f   // 0.5*ln(2*pi)
#define LOG2E 1.4426950408889634f

typedef float v2f __attribute__((ext_vector_type(2)));

__device__ __forceinline__ float4 ld4(const float* p){ return *(const float4*)p; }
__device__ __forceinline__ float rcpf(float x){ return __builtin_amdgcn_rcpf(x); }
__device__ __forceinline__ v2f bc2(float s){ return (v2f){s, s}; }
__device__ __forceinline__ v2f fma2(v2f a, v2f b, v2f c){ return __builtin_elementwise_fma(a, b, c); }

// DPP cross-lane reduce steps (VALU pipe ~2-4cyc vs ds_swizzle ~30cyc).
template<int CTRL>
__device__ __forceinline__ float dpp_add(float x){
  const int p = __builtin_amdgcn_update_dpp(0, __builtin_bit_cast(int, x),
                                            CTRL, 0xF, 0xF, true);
  return x + __builtin_bit_cast(float, p);
}
template<int CTRL>
__device__ __forceinline__ float dpp_max(float x){
  const int p = __builtin_amdgcn_update_dpp(0, __builtin_bit_cast(int, x),
                                            CTRL, 0xF, 0xF, true);
  return fmaxf(x, __builtin_bit_cast(float, p));
}
__device__ __forceinline__ float sum32(float s){
  s = dpp_add<0xB1>(s); s = dpp_add<0x4E>(s);
  s = dpp_add<0x141>(s); s = dpp_add<0x140>(s);
  s += __shfl_xor(s, 16);
  return s;
}

extern "C" __global__ void __launch_bounds__(NTH)
convcaps_em_kernel(const float* __restrict__ x, const float* __restrict__ wgt,
                   const float* __restrict__ beta_a, const float* __restrict__ beta_u,
                   float* __restrict__ out)
{
  __shared__ float sP[KK*PS];        // poses, xor-swizzled groups (18432 B)
  __shared__ float sA[KK];           // f = a/(a+eps) (1152 B)
  __shared__ float sPart[8*CC*33];   // wave partials t0|t1[16]|t2[16] (33792 B)
  __shared__ float sMu[CC*17];       // (2176 B)
  __shared__ float sNI2[CC*17];      // -0.5/sigma^2 (2176 B)
  __shared__ float sLs[CC], sLnA[CC], sAo[CC];   // 384 B
  // total ~58.1 KB -> 2 blocks/CU

  const int tid = threadIdx.x;
  const int n   = blockIdx.x;
  const int b   = n / 49;
  const int r49 = n - b*49;
  const int ohi = r49 / 7;
  const int owi = r49 - ohi*7;

  const float* xw = x + ((size_t)b*16 + (size_t)(ohi*2))*16*544 + (size_t)(owi*2)*544;

  const int c  = tid & 31;    // sweep layout: c in-wave (softmax over c)
  const int ks = tid >> 5;    // k-group 0..15
  const int w  = tid >> 6;    // wave 0..7
  const int cc = tid >> 4;    // stats layout: one thread per (cc, pp)
  const int pp = tid & 15;

  // ---- stage poses (xor-swizzled groups) ----
  for (int idx = tid; idx < KK*PS/4; idx += NTH) {   // 1152 float4s
    const int sp  = idx >> 7;
    const int ch4 = idx & 127;
    const int kh = sp/3, kw = sp - kh*3;
    const float4 v = ld4(&xw[kh*(16*544) + kw*544 + ch4*4]);
    const int k = sp*32 + (ch4 >> 2);
    const int g = ch4 & 3;
    *(float4*)&sP[(k<<4) + ((g ^ ((k>>1)&3))<<2)] = v;
  }
  // ---- stage activations ----
  if (tid < KK/4) {
    const int sp  = tid >> 3;
    const int bc4 = tid & 7;
    const int kh = sp/3, kw = sp - kh*3;
    const float4 v = ld4(&xw[kh*(16*544) + kw*544 + 512 + bc4*4]);
    *(float4*)&sA[sp*32 + bc4*4] = v;
  }
  __syncthreads();
  if (tid < KK) { const float a = sA[tid]; sA[tid] = a * rcpf(a + EPSF); }
  __syncthreads();

  float t0;
  v2f t1[8], t2[8];    // packed moment accumulators

  // ---- stats phase (R6-proven layout; unpack pairs at store) ----
  auto stats = [&](){
    t0 += __shfl_xor(t0, 32);
#pragma unroll
    for (int q = 0; q < 8; ++q) {
      t1[q].x += __shfl_xor(t1[q].x, 32);
      t1[q].y += __shfl_xor(t1[q].y, 32);
      t2[q].x += __shfl_xor(t2[q].x, 32);
      t2[q].y += __shfl_xor(t2[q].y, 32);
    }
    if ((tid & 32) == 0) {
      float* pr = &sPart[(w*CC + c)*33];
      pr[0] = t0;
#pragma unroll
      for (int q = 0; q < 8; ++q) {
        pr[1 + 2*q]     = t1[q].x;  pr[1 + 2*q + 1]  = t1[q].y;
        pr[17 + 2*q]    = t2[q].x;  pr[17 + 2*q + 1] = t2[q].y;
      }
    }
    __syncthreads();
    {
      float T0 = 0.f, T1 = 0.f, T2 = 0.f;
#pragma unroll
      for (int j = 0; j < 8; ++j) {
        const float* pr = &sPart[(j*CC + cc)*33];
        T0 += pr[0]; T1 += pr[1+pp]; T2 += pr[17+pp];
      }
      const float z   = rcpf(T0 + EPSF);
      const float mu  = T1 * z;
      const float s0  = T0 * z;
      const float var = fmaxf(T2*z - mu*mu*(2.f - s0), 0.f) + EPSF;
      sMu[cc*17 + pp]  = mu;
      sNI2[cc*17 + pp] = -0.5f * rcpf(var);
      float lsum = 0.5f * __logf(var);
      lsum = dpp_add<0xB1>(lsum); lsum = dpp_add<0x4E>(lsum);
      lsum = dpp_add<0x141>(lsum); lsum = dpp_add<0x140>(lsum);
      if (pp == 0) {
        const float cost = (16.f*beta_u[cc] + lsum) * T0;   // r_sum = T0
        const float ao = rcpf(1.f + __expf(-(LAMF*(beta_a[cc] - cost))));
        sAo[cc] = ao; sLnA[cc] = __logf(ao); sLs[cc] = lsum;
      }
    }
    __syncthreads();
  };

  const float4* wg4 = (const float4*)wgt;

  // v = P@W for one k into 8 packed v2f (16 fp32)
  auto compute_v = [&](v2f (&v)[8], const float4 (&P)[4],
                       const float4& W0, const float4& W1,
                       const float4& W2, const float4& W3){
    const v2f w0lo = {W0.x,W0.y}, w0hi = {W0.z,W0.w};
    const v2f w1lo = {W1.x,W1.y}, w1hi = {W1.z,W1.w};
    const v2f w2lo = {W2.x,W2.y}, w2hi = {W2.z,W2.w};
    const v2f w3lo = {W3.x,W3.y}, w3hi = {W3.z,W3.w};
#pragma unroll
    for (int i = 0; i < 4; ++i) {
      v2f lo = bc2(P[i].x) * w0lo;
      lo = fma2(bc2(P[i].y), w1lo, lo);
      lo = fma2(bc2(P[i].z), w2lo, lo);
      lo = fma2(bc2(P[i].w), w3lo, lo);
      v2f hi = bc2(P[i].x) * w0hi;
      hi = fma2(bc2(P[i].y), w1hi, hi);
      hi = fma2(bc2(P[i].z), w2hi, hi);
      hi = fma2(bc2(P[i].w), w3hi, hi);
      v[i*2] = lo; v[i*2+1] = hi;
    }
  };

  // ---- sweep 0 (it=0): r uniform -> rr = f/32, W software-pipelined ----
  t0 = 0.f;
#pragma unroll
  for (int q = 0; q < 8; ++q) { t1[q] = bc2(0.f); t2[q] = bc2(0.f); }
  {
    float4 cw0, cw1, cw2, cw3;
    {
      const size_t base = ((size_t)(ks*32 + c))*4;   // kt=0 -> k=ks
      cw0 = wg4[base]; cw1 = wg4[base+1]; cw2 = wg4[base+2]; cw3 = wg4[base+3];
    }
#pragma unroll 1
    for (int kt = 0; kt < KT; ++kt) {
      const int k = kt*KSG + ks;
      const int kn = ((kt+1 < KT) ? kt+1 : kt)*KSG + ks;
      float4 nw0, nw1, nw2, nw3;
      {
        const size_t base = ((size_t)(kn*32 + c))*4;
        nw0 = wg4[base]; nw1 = wg4[base+1]; nw2 = wg4[base+2]; nw3 = wg4[base+3];
      }
      const v2f w0lo = {cw0.x,cw0.y}, w0hi = {cw0.z,cw0.w};
      const v2f w1lo = {cw1.x,cw1.y}, w1hi = {cw1.z,cw1.w};
      const v2f w2lo = {cw2.x,cw2.y}, w2hi = {cw2.z,cw2.w};
      const v2f w3lo = {cw3.x,cw3.y}, w3hi = {cw3.z,cw3.w};
      const int sw = (k>>1)&3;
      const float* pb = &sP[k<<4];
      const float4 Pi[4] = { ld4(pb + ((0^sw)<<2)), ld4(pb + ((1^sw)<<2)),
                             ld4(pb + ((2^sw)<<2)), ld4(pb + ((3^sw)<<2)) };
      const float rr = sA[k] * (1.0f/32.0f);
      t0 += rr;
      const v2f rr2 = bc2(rr);
#pragma unroll
      for (int i = 0; i < 4; ++i) {
        v2f lo = bc2(Pi[i].x) * w0lo;
        lo = fma2(bc2(Pi[i].y), w1lo, lo);
        lo = fma2(bc2(Pi[i].z), w2lo, lo);
        lo = fma2(bc2(Pi[i].w), w3lo, lo);
        v2f hi = bc2(Pi[i].x) * w0hi;
        hi = fma2(bc2(Pi[i].y), w1hi, hi);
        hi = fma2(bc2(Pi[i].z), w2hi, hi);
        hi = fma2(bc2(Pi[i].w), w3hi, hi);
        const v2f mlo = rr2 * lo, mhi = rr2 * hi;
        t1[i*2]   += mlo;  t2[i*2]   = fma2(mlo, lo, t2[i*2]);
        t1[i*2+1] += mhi;  t2[i*2+1] = fma2(mhi, hi, t2[i*2+1]);
      }
      cw0 = nw0; cw1 = nw1; cw2 = nw2; cw3 = nw3;
    }
  }
  stats();

  // ---- sweeps 1,2: 2-stage rotation. Per iter: issue W(k)+sA(kp)+Pi(k),
  //      softmax+moments on PREVIOUS v (hides both latencies), compute v(k).
  for (int it = 1; it < 3; ++it) {
    // loop-invariant per (sweep, c): A = log2e*ni2, B = -2*log2e*ni2*mu,
    // G = log2e*(Sum ni2*mu^2 + lcv - M)
    v2f A2[8], B2[8];
    float gsum = 0.f;
#pragma unroll
    for (int q = 0; q < 8; ++q) {
      const v2f m2 = (v2f){ sMu[c*17 + 2*q],  sMu[c*17 + 2*q + 1] };
      const v2f n2 = (v2f){ sNI2[c*17 + 2*q], sNI2[c*17 + 2*q + 1] };
      const v2f nm = n2 * m2;
      A2[q] = bc2(LOG2E) * n2;
      B2[q] = bc2(-2.f*LOG2E) * nm;
      const v2f g2 = nm * m2;
      gsum += g2.x + g2.y;
    }
    float lcv = sLnA[c] - sLs[c] - 16.f*HL2PI;
    float M = lcv;
    M = dpp_max<0xB1>(M);  M = dpp_max<0x4E>(M);
    M = dpp_max<0x141>(M); M = dpp_max<0x140>(M);
    M = fmaxf(M, __shfl_xor(M, 16));
    const float G = LOG2E*(gsum + lcv - M);

    auto softmax_moments = [&](const v2f (&v)[8], float fA){
      v2f acc2 = bc2(0.f);
#pragma unroll
      for (int q = 0; q < 8; ++q) {
        const v2f h = fma2(A2[q], v[q], B2[q]);
        acc2 = fma2(h, v[q], acc2);
      }
      const float ex = acc2.x + acc2.y + G;      // log2-domain exponent <= ~0
      const float e = exp2f(ex);
      const float s = sum32(e);
      const float rr = e * rcpf(s + 1e-37f) * fA;   // r * a/(a+eps)
      t0 += rr;
      const v2f rr2 = bc2(rr);
#pragma unroll
      for (int q = 0; q < 8; ++q) {
        const v2f tmp = rr2 * v[q];
        t1[q] += tmp;
        t2[q] = fma2(tmp, v[q], t2[q]);
      }
    };

    t0 = 0.f;
#pragma unroll
    for (int q = 0; q < 8; ++q) { t1[q] = bc2(0.f); t2[q] = bc2(0.f); }

    v2f vA[8];
    // prologue (kt=0): load W(k0)+Pi(k0), compute vA. Latency exposed once.
    {
      const int k = ks;
      const size_t base = ((size_t)(k*32 + c))*4;
      const float4 w0 = wg4[base], w1 = wg4[base+1], w2 = wg4[base+2], w3 = wg4[base+3];
      const int sw = (k>>1)&3;
      const float* pb = &sP[k<<4];
      const float4 Pi[4] = { ld4(pb + ((0^sw)<<2)), ld4(pb + ((1^sw)<<2)),
                             ld4(pb + ((2^sw)<<2)), ld4(pb + ((3^sw)<<2)) };
      compute_v(vA, Pi, w0, w1, w2, w3);
    }
#pragma unroll 1
    for (int kt = 1; kt < KT; ++kt) {
      const int k  = kt*KSG + ks;
      const int kp = k - KSG;
      // (1) issue W(k) from L2 — consumed after softmax (~400cy later)
      const size_t base = ((size_t)(k*32 + c))*4;
      const float4 w0 = wg4[base], w1 = wg4[base+1], w2 = wg4[base+2], w3 = wg4[base+3];
      // (2) issue sA(kp) BEFORE Pi so its wait is lgkmcnt(4), not a drain
      const float fA = sA[kp];
      // (3) issue Pi(k) ds_reads — consumed after softmax
      const int sw = (k>>1)&3;
      const float* pb = &sP[k<<4];
      const float4 Pi[4] = { ld4(pb + ((0^sw)<<2)), ld4(pb + ((1^sw)<<2)),
                             ld4(pb + ((2^sw)<<2)), ld4(pb + ((3^sw)<<2)) };
      // (4) softmax + moments on previous k's v — pure VALU, hides (1)+(3)
      softmax_moments(vA, fA);
      // (5) compute v(k) — waits land here
      compute_v(vA, Pi, w0, w1, w2, w3);
    }
    // epilogue: softmax+moments for the last k
    softmax_moments(vA, sA[(KT-1)*KSG + ks]);
    stats();
  }

  // ---- epilogue ----
  out[(size_t)n*544 + tid] = sMu[(tid>>4)*17 + (tid&15)];
  if (tid < CC) out[(size_t)n*544 + 512 + tid] = sAo[tid];
}

extern "C" void kernel_launch(void* const* d_in, const int* in_sizes, int n_in,
                              void* d_out, int out_size, void* d_ws, size_t ws_size,
                              hipStream_t stream) {
  (void)in_sizes; (void)n_in; (void)d_ws; (void)ws_size; (void)out_size;
  const float* x  = (const float*)d_in[0];
  const float* w  = (const float*)d_in[1];
  const float* ba = (const float*)d_in[2];
  const float* bu = (const float*)d_in[3];
  float* out = (float*)d_out;
  convcaps_em_kernel<<<dim3(392), dim3(NTH), 0, stream>>>(x, w, ba, bu, out);
}